// Round 10
// baseline (500.768 us; speedup 1.0000x reference)
//
#include <hip/hip_runtime.h>
#include <cstdint>

#define SEQ 2048
#define BATCH 2
#define NTOK 4096      // B*S
#define HID 2048
#define NH 32
#define NKV 4
#define HD 128
#define QKV_O 5120     // (32+8)*128

typedef __attribute__((ext_vector_type(8))) short short8;
typedef __attribute__((ext_vector_type(8))) unsigned short u16x8;
typedef __attribute__((ext_vector_type(4))) unsigned short u16x4;
typedef __attribute__((ext_vector_type(4))) float f32x4;

__device__ __forceinline__ float bf2f(unsigned short u) {
  union { unsigned int i; float f; } v; v.i = ((unsigned int)u) << 16; return v.f;
}
__device__ __forceinline__ unsigned short f2bf(float f) {
  union { float f; unsigned int i; } v; v.f = f;
  unsigned int r = v.i + 0x7FFFu + ((v.i >> 16) & 1u);
  return (unsigned short)(r >> 16);
}

// async global->LDS, 16 B per lane. LDS dest is wave-uniform base + lane*16.
__device__ __forceinline__ void load_lds16(const void* g, void* l) {
  __builtin_amdgcn_global_load_lds((const __attribute__((address_space(1))) unsigned int*)g,
                                   (__attribute__((address_space(3))) unsigned int*)l, 16, 0, 0);
}

// native v_exp_f32 (2^x), no libm range handling
__device__ __forceinline__ float exp2n(float x) { return __builtin_amdgcn_exp2f(x); }

// ---------------------------------------------------------------------------
// Fused fp32 -> bf16 for all 5 input arrays; blockIdx.y selects the array.
// ---------------------------------------------------------------------------
__global__ __launch_bounds__(256) void convert5(
    const float* __restrict__ s0, unsigned short* __restrict__ d0, int n0,
    const float* __restrict__ s1, unsigned short* __restrict__ d1, int n1,
    const float* __restrict__ s2, unsigned short* __restrict__ d2, int n2,
    const float* __restrict__ s3, unsigned short* __restrict__ d3, int n3,
    const float* __restrict__ s4, unsigned short* __restrict__ d4, int n4_) {
  const float* s; unsigned short* d; int n;
  switch (blockIdx.y) {
    case 0: s = s0; d = d0; n = n0; break;
    case 1: s = s1; d = d1; n = n1; break;
    case 2: s = s2; d = d2; n = n2; break;
    case 3: s = s3; d = d3; n = n3; break;
    default: s = s4; d = d4; n = n4_; break;
  }
  int i = blockIdx.x * blockDim.x + threadIdx.x;
  int stride = gridDim.x * blockDim.x;
  for (; i < n; i += stride) {
    f32x4 v = *(const f32x4*)(s + 4 * (size_t)i);
    u16x4 o;
    o.x = f2bf(v.x); o.y = f2bf(v.y); o.z = f2bf(v.z); o.w = f2bf(v.w);
    *(u16x4*)(d + 4 * (size_t)i) = o;
  }
}

// ---------------------------------------------------------------------------
// out4 += part4 (fp32), grid-stride. Reduce for split-K.
// ---------------------------------------------------------------------------
__global__ __launch_bounds__(256) void reduce_add(float* __restrict__ out,
                                                  const float* __restrict__ part, int n4) {
  int i = blockIdx.x * blockDim.x + threadIdx.x;
  int stride = gridDim.x * blockDim.x;
  for (; i < n4; i += stride) {
    f32x4 a = *(const f32x4*)(out + 4 * (size_t)i);
    f32x4 b = *(const f32x4*)(part + 4 * (size_t)i);
    a.x += b.x; a.y += b.y; a.z += b.z; a.w += b.w;
    *(f32x4*)(out + 4 * (size_t)i) = a;
  }
}

// ---------------------------------------------------------------------------
// 256x256-tile GEMM, 8-PHASE schedule (m201-style T3+T4+T2+T5 port).
// BK=64 K-tiles; 512 thr; LDS 128 KiB dbuf (proven-0-conflict swizzle).
// Quadrant decomposition: phase q of a K-tile computes block C-quadrant
// (Qm=q>>1, Qn=q&1); wave w owns a 64x32 piece (rows Qm*128+(w>>2)*64,
// cols Qn*128+(w&3)*32) -> 16 MFMA/phase. Phase q reads ONLY A-half Qm /
// B-half Qn, so halves die mid-tile:
//   Ah0 dead after phase1, Bh0 after phase2 -> tile kt+2's Ah0/Bh0 may be
//   staged into the live buffer at phases 2/3. Stage slots per tile:
//   p0:Bh1(t+1) p1:Ah1(t+1) p2:Ah0(t+2) p3:Bh0(t+2)  (1 half = 2 loads/thr).
// Tile-top wait: vmcnt(4) -- drains everything except the 2 youngest
// half-stages (tile t+2's Ah0/Bh0) => tile t fully landed, pipeline never
// empties. Final tile uses vmcnt(0) (its stages-for-future are suppressed,
// so counted-wait would under-drain). B frags read once/tile, held in regs.
// SPLIT: gridDim.z=2 halves K; z=0 -> C0 (fp32 partial), z=1 -> C1.
// ---------------------------------------------------------------------------
template <bool OUT_F32, bool SPLIT>
__global__ __launch_bounds__(512, 2) void gemm256_8p(
    const unsigned short* __restrict__ A, const unsigned short* __restrict__ B,
    void* __restrict__ C0, void* __restrict__ C1,
    int lda, int ldb, int ldc, int Kloop) {
  __shared__ alignas(16) unsigned short As[2][256 * 64];
  __shared__ alignas(16) unsigned short Bs[2][256 * 64];

  const int t = threadIdx.x;
  const int lane = t & 63, w = t >> 6;
  const int fr = lane & 15, g = lane >> 4;
  const int wr = (w >> 2) * 64;                      // row base in A-half
  const int wc = (w & 3) * 32;                       // col base in B-half
  const size_t m0 = (size_t)blockIdx.y * 256;
  const size_t n0 = (size_t)blockIdx.x * 256;
  const int kbase = SPLIT ? (int)blockIdx.z * Kloop : 0;
  void* Cv = (SPLIT && blockIdx.z) ? C1 : C0;

  // staging geometry (identical to proven gemm256; 0 bank conflicts)
  const int srow = w * 8 + (lane >> 3);
  const int sch = (lane & 7) ^ ((lane >> 3) & 7);
  const unsigned short* gA[4];
  const unsigned short* gB[4];
#pragma unroll
  for (int i = 0; i < 4; i++) {
    gA[i] = A + (m0 + i * 64 + srow) * (size_t)lda + kbase + sch * 8;
    gB[i] = B + (n0 + i * 64 + srow) * (size_t)ldb + kbase + sch * 8;
  }

  // one half-tile stage = rows [half*128, half*128+128) = 2 loads/thread
  auto stA = [&](int half, int k0, int bi) {
    load_lds16(gA[2 * half] + k0,     &As[bi][(half * 1024 + w * 64) * 8]);
    load_lds16(gA[2 * half + 1] + k0, &As[bi][(half * 1024 + 512 + w * 64) * 8]);
  };
  auto stB = [&](int half, int k0, int bi) {
    load_lds16(gB[2 * half] + k0,     &Bs[bi][(half * 1024 + w * 64) * 8]);
    load_lds16(gB[2 * half + 1] + k0, &Bs[bi][(half * 1024 + 512 + w * 64) * 8]);
  };

  const int ck0 = ((0 + g) ^ (fr & 7)) * 8;          // swizzled chunk, ks=0
  const int ck1 = ((4 + g) ^ (fr & 7)) * 8;          // swizzled chunk, ks=1

  f32x4 acc[4][4][2] = {};                           // [quadrant][mf][nf]
  const int nk = Kloop / 64;

  // prologue: tile0 fully + tile1's Ah0/Bh0 (pipeline primed, 12 loads)
  stA(0, 0, 0); stB(0, 0, 0); stB(1, 0, 0); stA(1, 0, 0);
  if (nk > 1) { stA(0, 64, 1); stB(0, 64, 1); }

  for (int kt = 0; kt < nk; kt++) {
    const int cur = kt & 1;
    const unsigned short* Ac = As[cur];
    const unsigned short* Bc = Bs[cur];
    const int kn1 = (kt + 1) * 64, kn2 = (kt + 2) * 64;

    // tile-top: counted wait (never 0 mid-loop), then block-wide ready
    if (kt + 1 < nk) asm volatile("s_waitcnt vmcnt(4)" ::: "memory");
    else             asm volatile("s_waitcnt vmcnt(0)" ::: "memory");
    __builtin_amdgcn_s_barrier();
    __builtin_amdgcn_sched_barrier(0);

    short8 Af[4][2], Bf0[2][2], Bf1[2][2];

    // ---- phase 0: quadrant (0,0) -- reads Ah0, Bh0
    if (kt + 1 < nk) stB(1, kn1, cur ^ 1);
#pragma unroll
    for (int mf = 0; mf < 4; mf++) {
      Af[mf][0] = *(const short8*)&Ac[(wr + mf * 16 + fr) * 64 + ck0];
      Af[mf][1] = *(const short8*)&Ac[(wr + mf * 16 + fr) * 64 + ck1];
    }
#pragma unroll
    for (int nf = 0; nf < 2; nf++) {
      Bf0[nf][0] = *(const short8*)&Bc[(wc + nf * 16 + fr) * 64 + ck0];
      Bf0[nf][1] = *(const short8*)&Bc[(wc + nf * 16 + fr) * 64 + ck1];
    }
    __builtin_amdgcn_s_setprio(1);
#pragma unroll
    for (int mf = 0; mf < 4; mf++)
#pragma unroll
      for (int nf = 0; nf < 2; nf++) {
        acc[0][mf][nf] = __builtin_amdgcn_mfma_f32_16x16x32_bf16(Af[mf][0], Bf0[nf][0], acc[0][mf][nf], 0, 0, 0);
        acc[0][mf][nf] = __builtin_amdgcn_mfma_f32_16x16x32_bf16(Af[mf][1], Bf0[nf][1], acc[0][mf][nf], 0, 0, 0);
      }
    __builtin_amdgcn_s_setprio(0);
    __builtin_amdgcn_s_barrier();
    __builtin_amdgcn_sched_barrier(0);

    // ---- phase 1: quadrant (0,1) -- reads Bh1 (A held in regs)
    if (kt + 1 < nk) stA(1, kn1, cur ^ 1);
#pragma unroll
    for (int nf = 0; nf < 2; nf++) {
      Bf1[nf][0] = *(const short8*)&Bc[(128 + wc + nf * 16 + fr) * 64 + ck0];
      Bf1[nf][1] = *(const short8*)&Bc[(128 + wc + nf * 16 + fr) * 64 + ck1];
    }
    __builtin_amdgcn_s_setprio(1);
#pragma unroll
    for (int mf = 0; mf < 4; mf++)
#pragma unroll
      for (int nf = 0; nf < 2; nf++) {
        acc[1][mf][nf] = __builtin_amdgcn_mfma_f32_16x16x32_bf16(Af[mf][0], Bf1[nf][0], acc[1][mf][nf], 0, 0, 0);
        acc[1][mf][nf] = __builtin_amdgcn_mfma_f32_16x16x32_bf16(Af[mf][1], Bf1[nf][1], acc[1][mf][nf], 0, 0, 0);
      }
    __builtin_amdgcn_s_setprio(0);
    __builtin_amdgcn_s_barrier();
    __builtin_amdgcn_sched_barrier(0);

    // ---- phase 2: quadrant (1,0) -- reads Ah1; Ah0(kt) is dead -> stage kt+2
    if (kt + 2 < nk) stA(0, kn2, cur);
#pragma unroll
    for (int mf = 0; mf < 4; mf++) {
      Af[mf][0] = *(const short8*)&Ac[(128 + wr + mf * 16 + fr) * 64 + ck0];
      Af[mf][1] = *(const short8*)&Ac[(128 + wr + mf * 16 + fr) * 64 + ck1];
    }
    __builtin_amdgcn_s_setprio(1);
#pragma unroll
    for (int mf = 0; mf < 4; mf++)
#pragma unroll
      for (int nf = 0; nf < 2; nf++) {
        acc[2][mf][nf] = __builtin_amdgcn_mfma_f32_16x16x32_bf16(Af[mf][0], Bf0[nf][0], acc[2][mf][nf], 0, 0, 0);
        acc[2][mf][nf] = __builtin_amdgcn_mfma_f32_16x16x32_bf16(Af[mf][1], Bf0[nf][1], acc[2][mf][nf], 0, 0, 0);
      }
    __builtin_amdgcn_s_setprio(0);
    __builtin_amdgcn_s_barrier();
    __builtin_amdgcn_sched_barrier(0);

    // ---- phase 3: quadrant (1,1) -- regs only; Bh0(kt) dead -> stage kt+2
    if (kt + 2 < nk) stB(0, kn2, cur);
    __builtin_amdgcn_s_setprio(1);
#pragma unroll
    for (int mf = 0; mf < 4; mf++)
#pragma unroll
      for (int nf = 0; nf < 2; nf++) {
        acc[3][mf][nf] = __builtin_amdgcn_mfma_f32_16x16x32_bf16(Af[mf][0], Bf1[nf][0], acc[3][mf][nf], 0, 0, 0);
        acc[3][mf][nf] = __builtin_amdgcn_mfma_f32_16x16x32_bf16(Af[mf][1], Bf1[nf][1], acc[3][mf][nf], 0, 0, 0);
      }
    __builtin_amdgcn_s_setprio(0);
    __builtin_amdgcn_s_barrier();
    __builtin_amdgcn_sched_barrier(0);
  }

  // epilogue: C/D layout col=lane&15, row=(lane>>4)*4+reg
#pragma unroll
  for (int q = 0; q < 4; q++) {
    const int Qm = q >> 1, Qn = q & 1;
#pragma unroll
    for (int mf = 0; mf < 4; mf++)
#pragma unroll
      for (int nf = 0; nf < 2; nf++) {
        size_t row = m0 + Qm * 128 + wr + mf * 16 + g * 4;
        size_t col = n0 + Qn * 128 + wc + nf * 16 + fr;
#pragma unroll
        for (int r = 0; r < 4; r++) {
          if (OUT_F32) ((float*)Cv)[(row + r) * ldc + col] = acc[q][mf][nf][r];
          else ((unsigned short*)Cv)[(row + r) * ldc + col] = f2bf(acc[q][mf][nf][r]);
        }
      }
  }
}

// ---------------------------------------------------------------------------
// 128x128-tile GEMM (proven R0-R3): C = A[M,K] * B[N,K]^T.
// Used for the KV slice of K1 (N=1024 -> 256 blocks, 2/CU, exactly 1 round).
// ---------------------------------------------------------------------------
template <bool OUT_F32>
__global__ __launch_bounds__(256) void gemm_bt_bf16(
    const unsigned short* __restrict__ A, const unsigned short* __restrict__ B,
    void* __restrict__ Cv, int lda, int ldb, int ldc, int K) {
  __shared__ alignas(16) unsigned short As[128 * 32];
  __shared__ alignas(16) unsigned short Bs[128 * 32];

  const int t    = threadIdx.x;
  const int lane = t & 63;
  const int w    = t >> 6;
  const int wm   = (w >> 1) * 64;
  const int wn   = (w & 1) * 64;
  const size_t m0 = (size_t)blockIdx.y * 128;
  const size_t n0 = (size_t)blockIdx.x * 128;

  f32x4 acc[4][4] = {};

  const int srow = w * 32 + (lane >> 2);
  const int scol = (lane & 3) * 8;
  const unsigned short* gA0 = &A[(m0 + srow) * (size_t)lda + scol];
  const unsigned short* gA1 = gA0 + 16 * (size_t)lda;
  const unsigned short* gB0 = &B[(n0 + srow) * (size_t)ldb + scol];
  const unsigned short* gB1 = gB0 + 16 * (size_t)ldb;
  unsigned short* lA0 = &As[(w * 32) * 32];
  unsigned short* lA1 = &As[(w * 32 + 16) * 32];
  unsigned short* lB0 = &Bs[(w * 32) * 32];
  unsigned short* lB1 = &Bs[(w * 32 + 16) * 32];

  const int fr = lane & 15;
  const int kb = (lane >> 4) * 8;

  for (int k0 = 0; k0 < K; k0 += 32) {
    load_lds16(gA0 + k0, lA0);
    load_lds16(gA1 + k0, lA1);
    load_lds16(gB0 + k0, lB0);
    load_lds16(gB1 + k0, lB1);
    __syncthreads();
    short8 af[4], bf[4];
#pragma unroll
    for (int mt = 0; mt < 4; mt++) af[mt] = *(const short8*)&As[(wm + mt * 16 + fr) * 32 + kb];
#pragma unroll
    for (int nt = 0; nt < 4; nt++) bf[nt] = *(const short8*)&Bs[(wn + nt * 16 + fr) * 32 + kb];
#pragma unroll
    for (int mt = 0; mt < 4; mt++)
#pragma unroll
      for (int nt = 0; nt < 4; nt++)
        acc[mt][nt] = __builtin_amdgcn_mfma_f32_16x16x32_bf16(af[mt], bf[nt], acc[mt][nt], 0, 0, 0);
    __syncthreads();
  }

  const int r4 = (lane >> 4) * 4;
  const int cc = lane & 15;
#pragma unroll
  for (int mt = 0; mt < 4; mt++)
#pragma unroll
    for (int nt = 0; nt < 4; nt++) {
      size_t row = m0 + wm + mt * 16 + r4;
      size_t col = n0 + wn + nt * 16 + cc;
#pragma unroll
      for (int r = 0; r < 4; r++) {
        if (OUT_F32) ((float*)Cv)[(row + r) * ldc + col] = acc[mt][nt][r];
        else ((unsigned short*)Cv)[(row + r) * ldc + col] = f2bf(acc[mt][nt][r]);
      }
    }
}

// ---------------------------------------------------------------------------
// RoPE cos/sin table per token: tab[tok*64+j] = {cos,sin}(pos[tok]*invfreq_j).
// ---------------------------------------------------------------------------
__global__ __launch_bounds__(64) void rope_tab(const int* __restrict__ pos,
                                               float2* __restrict__ tab) {
  const int tok = blockIdx.x;
  const int j = threadIdx.x;
  float p = (float)pos[tok];
  float inv_freq = expf((float)j * (-13.815510557964274f / 64.0f));  // 1e6^(-j/64)
  float ang = p * inv_freq;
  float2 cs; cs.x = cosf(ang); cs.y = sinf(ang);
  tab[tok * 64 + j] = cs;
}

// ---------------------------------------------------------------------------
// RMSNorm + RoPE, IN PLACE on qkv. 256 thr = 4 waves = 4 heads per block.
// ---------------------------------------------------------------------------
__global__ __launch_bounds__(256) void normrope(
    unsigned short* __restrict__ qkv, const float2* __restrict__ tab,
    const unsigned short* __restrict__ qw, const unsigned short* __restrict__ kw) {
  const int wv   = threadIdx.x >> 6;
  const int lane = threadIdx.x & 63;
  const int h    = blockIdx.x * 4 + wv;              // 0..35 (32 q + 4 k)
  const int tok  = blockIdx.z * SEQ + blockIdx.y;

  const unsigned short* w = (h < NH) ? qw : kw;
  const size_t src = (size_t)tok * QKV_O + (size_t)h * HD;

  float x1 = bf2f(qkv[src + lane]);
  float x2 = bf2f(qkv[src + lane + 64]);
  float ss = x1 * x1 + x2 * x2;
#pragma unroll
  for (int off = 32; off; off >>= 1) ss += __shfl_xor(ss, off);
  float r = rsqrtf(ss * (1.0f / 128.0f) + 1e-6f);
  float n1 = x1 * r * bf2f(w[lane]);
  float n2 = x2 * r * bf2f(w[lane + 64]);

  float2 cs = tab[tok * 64 + lane];
  qkv[src + lane]      = f2bf(n1 * cs.x - n2 * cs.y);
  qkv[src + lane + 64] = f2bf(n2 * cs.x + n1 * cs.y);
}

// ---------------------------------------------------------------------------
// V transpose: vt[b][kvh][d][s] <- qkv v-slot. One block per (kv-tile 64, kvh, b).
// ---------------------------------------------------------------------------
__global__ __launch_bounds__(256) void transpose_v(const unsigned short* __restrict__ qkv,
                                                   unsigned short* __restrict__ vt) {
  __shared__ alignas(16) unsigned short Vs[64][136];
  const int k0 = blockIdx.x * 64, kvh = blockIdx.y, b = blockIdx.z;
  const int t = threadIdx.x;
  const int voff = (NH + NKV) * HD + kvh * HD;
  {
    const int row = t >> 2, cb = (t & 3) * 8;
    const size_t gb = (size_t)(b * SEQ + k0 + row) * QKV_O + voff;
#pragma unroll
    for (int r = 0; r < 4; r++)
      *(uint4*)&Vs[row][cb + 32 * r] = *(const uint4*)&qkv[gb + cb + 32 * r];
  }
  __syncthreads();
  const int d = t >> 1, half = t & 1;
  const size_t ob = ((size_t)((b * NKV + kvh) * HD + d)) * SEQ + k0 + half * 32;
#pragma unroll
  for (int i = 0; i < 4; i++) {
    u16x8 vv;
#pragma unroll
    for (int j = 0; j < 8; j++) vv[j] = Vs[half * 32 + i * 8 + j][d];
    *(u16x8*)&vt[ob + i * 8] = vv;
  }
}

// ---------------------------------------------------------------------------
// MFMA causal GQA flash attention (v8, frozen: proven 110.4 us).
// ---------------------------------------------------------------------------
__global__ __launch_bounds__(512, 4) void flash_mfma(unsigned short* __restrict__ qkv,
                                                     const unsigned short* __restrict__ vt) {
  __shared__ alignas(16) unsigned short Kbuf[2][64 * 128];
  __shared__ alignas(16) unsigned short Vbuf[2][128 * 64];
  __shared__ alignas(16) unsigned short Ps[8][16 * 64];

  const int p = (int)blockIdx.x;                       // pair index 0..7
  const int h = blockIdx.y, b = blockIdx.z;
  const int t = threadIdx.x;
  const int lane = t & 63, w = t >> 6;
  const int c = lane & 15, g = lane >> 4;
  const int kvh = h >> 3;                              // GQA 32->4
  const int koff = NH * HD + kvh * HD;
  const float scale2 = 0.12751745f;                    // 128^-0.5 * log2(e)
  const int swz = c & 7;                               // 3-bit swz (V, P tiles)
  const int nqt = SEQ / 128;                           // 16

  const int rK0 = t >> 4,         jK0 = (t & 15) ^ (rK0 & 15);
  const int rK1 = (t + 512) >> 4, jK1 = ((t + 512) & 15) ^ (rK1 & 15);
  const int dV0 = t >> 3,         jV0 = (t & 7) ^ (dV0 & 7);
  const int dV1 = (t + 512) >> 3, jV1 = ((t + 512) & 7) ^ (dV1 & 7);
  const unsigned short* gK0 = qkv + (size_t)(b * SEQ + rK0) * QKV_O + koff + jK0 * 8;
  const unsigned short* gK1 = qkv + (size_t)(b * SEQ + rK1) * QKV_O + koff + jK1 * 8;
  const unsigned short* gV0 = vt + ((size_t)(b * NKV + kvh) * HD + dV0) * SEQ + jV0 * 8;
  const unsigned short* gV1 = vt + ((size_t)(b * NKV + kvh) * HD + dV1) * SEQ + jV1 * 8;

  auto stage = [&](int k0s, int bi) {
    load_lds16(gK0 + (size_t)k0s * QKV_O, &Kbuf[bi][(w * 64) * 8]);
    load_lds16(gK1 + (size_t)k0s * QKV_O, &Kbuf[bi][(w * 64 + 512) * 8]);
    load_lds16(gV0 + k0s, &Vbuf[bi][(w * 64) * 8]);
    load_lds16(gV1 + k0s, &Vbuf[bi][(w * 64 + 512) * 8]);
  };

  for (int job = 0; job < 2; job++) {
    const int qt = job == 0 ? (nqt - 1 - p) : p;       // heavy job first
    const int q0 = qt * 128;
    const int nkt = 2 * qt + 2;

    stage(0, 0);   // prologue: tile 0 -> buf 0

    short8 qf[4];
    {
      const size_t qr = (size_t)(b * SEQ + q0 + w * 16 + c) * QKV_O + (size_t)h * HD;
#pragma unroll
      for (int ks = 0; ks < 4; ks++)
        qf[ks] = *(const short8*)&qkv[qr + ks * 32 + g * 8];
    }

    f32x4 O[8] = {};
    float m_i = -1e30f, l_i = 0.0f;                    // m in log2 domain

    for (int kt = 0; kt < nkt; kt++) {
      const int cur = kt & 1;
      asm volatile("s_waitcnt vmcnt(0)" ::: "memory");
      __builtin_amdgcn_s_barrier();
      __builtin_amdgcn_sched_barrier(0);
      if (kt + 1 < nkt) stage((kt + 1) * 64, cur ^ 1);

      const unsigned short* Kc = Kbuf[cur];
      const unsigned short* Vc = Vbuf[cur];

      f32x4 sc[4];
#pragma unroll
      for (int mt = 0; mt < 4; mt++) sc[mt] = (f32x4){0.f, 0.f, 0.f, 0.f};
      __builtin_amdgcn_s_setprio(1);
#pragma unroll
      for (int ks = 0; ks < 4; ks++) {
#pragma unroll
        for (int mt = 0; mt < 4; mt++) {
          short8 kf = *(const short8*)&Kc[(mt * 16 + c) * 128 + (((ks * 4 + g) ^ c) * 8)];
          sc[mt] = __builtin_amdgcn_mfma_f32_16x16x32_bf16(kf, qf[ks], sc[mt], 0, 0, 0);
        }
      }
      __builtin_amdgcn_s_setprio(0);

      const int k0 = kt * 64;
      const int qrow = q0 + w * 16 + c;
      const bool need_mask = (k0 + 63 > q0 + w * 16);
#pragma unroll
      for (int mt = 0; mt < 4; mt++)
#pragma unroll
        for (int r = 0; r < 4; r++) {
          float s = sc[mt][r];
          if (need_mask && (k0 + mt * 16 + g * 4 + r > qrow)) s = -3.0e38f;
          sc[mt][r] = s;
        }
      // max via groups-of-3 (v_max3-fusable), depth 3
      float ma = fmaxf(fmaxf(sc[0][0], sc[0][1]), sc[0][2]);
      float mb = fmaxf(fmaxf(sc[0][3], sc[1][0]), sc[1][1]);
      float mc = fmaxf(fmaxf(sc[1][2], sc[1][3]), sc[2][0]);
      float md = fmaxf(fmaxf(sc[2][1], sc[2][2]), sc[2][3]);
      float me = fmaxf(fmaxf(sc[3][0], sc[3][1]), sc[3][2]);
      float mx = fmaxf(fmaxf(fmaxf(ma, mb), fmaxf(mc, md)), fmaxf(me, sc[3][3]));
      mx = fmaxf(mx, __shfl_xor(mx, 16));
      mx = fmaxf(mx, __shfl_xor(mx, 32));
      float mx2 = mx * scale2;                         // log2 domain

      if (!__all(mx2 - m_i <= 11.54156f)) {            // 8 * log2(e)
        float m_new = fmaxf(m_i, mx2);
        float alpha = exp2n(m_i - m_new);
        f32x4 a4;
#pragma unroll
        for (int r = 0; r < 4; r++) a4[r] = __shfl(alpha, g * 4 + r);
#pragma unroll
        for (int nt = 0; nt < 8; nt++)
#pragma unroll
          for (int r = 0; r < 4; r++) O[nt][r] *= a4[r];
        l_i *= alpha;
        m_i = m_new;
      }

      float psum = 0.0f;
#pragma unroll
      for (int mt = 0; mt < 4; mt++) {
        float pv[4];
#pragma unroll
        for (int r = 0; r < 4; r++) {
          pv[r] = exp2n(__builtin_fmaf(sc[mt][r], scale2, -m_i));
          psum += pv[r];
        }
        unsigned int pk0, pk1;
        asm("v_cvt_pk_bf16_f32 %0, %1, %2" : "=v"(pk0) : "v"(pv[0]), "v"(pv[1]));
        asm("v_cvt_pk_bf16_f32 %0, %1, %2" : "=v"(pk1) : "v"(pv[2]), "v"(pv[3]));
        uint2 pk; pk.x = pk0; pk.y = pk1;
        *(uint2*)&Ps[w][c * 64 + (((mt * 2 + (g >> 1)) ^ swz) * 8) + (g & 1) * 4] = pk;
      }
      psum += __shfl_xor(psum, 16);
      psum += __shfl_xor(psum, 32);
      l_i += psum;

      __builtin_amdgcn_s_setprio(1);
#pragma unroll
      for (int ks = 0; ks < 2; ks++) {
        short8 pf = *(const short8*)&Ps[w][c * 64 + (((ks * 4 + g) ^ swz) * 8)];
#pragma unroll
        for (int nt = 0; nt < 8; nt++) {
          short8 vf = *(const short8*)&Vc[(nt * 16 + c) * 64 + (((ks * 4 + g) ^ swz) * 8)];
          O[nt] = __builtin_amdgcn_mfma_f32_16x16x32_bf16(pf, vf, O[nt], 0, 0, 0);
        }
      }
      __builtin_amdgcn_s_setprio(0);
    }

    f32x4 l4;
#pragma unroll
    for (int r = 0; r < 4; r++) l4[r] = __shfl(l_i, g * 4 + r);
    f32x4 li;
#pragma unroll
    for (int r = 0; r < 4; r++) li[r] = 1.0f / l4[r];
#pragma unroll
    for (int nt = 0; nt < 8; nt++)
#pragma unroll
      for (int r = 0; r < 4; r++) {
        size_t addr = (size_t)(b * SEQ + q0 + w * 16 + g * 4 + r) * QKV_O + h * HD + nt * 16 + c;
        qkv[addr] = f2bf(O[nt][r] * li[r]);
      }
  }
}

// ---------------------------------------------------------------------------
extern "C" void kernel_launch(void* const* d_in, const int* in_sizes, int n_in,
                              void* d_out, int out_size, void* d_ws, size_t ws_size,
                              hipStream_t stream) {
  const float* hidden_f = (const float*)d_in[0];
  const int* positions  = (const int*)d_in[1];
  const float* wqkv_f   = (const float*)d_in[2];
  const float* wo_f     = (const float*)d_in[3];
  const float* qn_f     = (const float*)d_in[4];
  const float* kn_f     = (const float*)d_in[5];
  float* out            = (float*)d_out;  // reference output dtype is float32

  char* ws = (char*)d_ws;
  unsigned short* hidden_c = (unsigned short*)ws;                    // 16,777,216
  unsigned short* wqkv_c   = (unsigned short*)(ws + 16777216);       // 20,971,520
  unsigned short* wo_c     = (unsigned short*)(ws + 37748736);       // 16,777,216
  unsigned short* qn_c     = (unsigned short*)(ws + 54525952);       // 256
  unsigned short* kn_c     = (unsigned short*)(ws + 54526208);       // 256
  unsigned short* qkv      = (unsigned short*)(ws + 54526464);       // 41,943,040
  unsigned short* vt_g     = (unsigned short*)(ws + 96469504);       // 4,194,304  (total ~96 MiB)
  // rope table REUSES the hidden_c region (dead after K1): 2 MiB
  float2* rtab             = (float2*)ws;
  // split-K fp32 partial for K4 (33.5 MB) overlays dead hidden_c+wqkv_c
  float* p0                = (float*)ws;

  // converts: one dispatch, blockIdx.y selects array
  convert5<<<dim3(512, 5), 256, 0, stream>>>(
      hidden_f, hidden_c, NTOK * HID / 4,
      wqkv_f, wqkv_c, QKV_O * HID / 4,
      wo_f, wo_c, HID * NH * HD / 4,
      qn_f, qn_c, HD / 4,
      kn_f, kn_c, HD / 4);

  // K1a: Q slice: qkv[:, :4096] = hidden @ w_qkv[:4096]^T (4096x4096, K=2048)
  // 8-phase schedule, 16x16 = 256 blocks = exactly 1 round.
  gemm256_8p<false, false><<<dim3(NH * HD / 256, NTOK / 256), 512, 0, stream>>>(
      hidden_c, wqkv_c, qkv, qkv, HID, HID, QKV_O, HID);
  // K1b: KV slice: qkv[:, 4096:5120] = hidden @ w_qkv[4096:]^T (4096x1024)
  gemm_bt_bf16<false><<<dim3(2 * NKV * HD / 128, NTOK / 128), 256, 0, stream>>>(
      hidden_c, wqkv_c + (size_t)(NH * HD) * HID, qkv + NH * HD, HID, HID, QKV_O, HID);
  // K1c: rope table (hidden_c dead now; table overwrites it)
  rope_tab<<<NTOK, 64, 0, stream>>>(positions, rtab);
  // K2: rmsnorm + rope, in place on q & k head slots (4 heads/block)
  normrope<<<dim3((NH + NKV) / 4, SEQ, BATCH), 256, 0, stream>>>(qkv, rtab, qn_c, kn_c);
  // K2b: V transpose into vt_g
  transpose_v<<<dim3(SEQ / 64, NKV, BATCH), 256, 0, stream>>>(qkv, vt_g);
  // K3: MFMA causal GQA attention (v8, frozen)
  flash_mfma<<<dim3(SEQ / 256, NH, BATCH), 512, 0, stream>>>(qkv, vt_g);
  // K4: out = attn @ w_o^T (4096 x 2048, K=4096), 8-phase split-K=2:
  // 8x16x2 = 256 blocks = 1 round; z=0 -> p0 partial, z=1 -> out.
  gemm256_8p<true, true><<<dim3(HID / 256, NTOK / 256, 2), 512, 0, stream>>>(
      qkv, wo_c, p0, out, QKV_O, NH * HD, HID, NH * HD / 2);
  // K4b: out += p0
  reduce_add<<<2048, 256, 0, stream>>>(out, p0, NTOK * HID / 4);
}

// Round 11
// 479.428 us; speedup vs baseline: 1.0445x; 1.0445x over previous
//
#include <hip/hip_runtime.h>
#include <cstdint>

#define SEQ 2048
#define BATCH 2
#define NTOK 4096      // B*S
#define HID 2048
#define NH 32
#define NKV 4
#define HD 128
#define QKV_O 5120     // (32+8)*128

typedef __attribute__((ext_vector_type(8))) short short8;
typedef __attribute__((ext_vector_type(8))) unsigned short u16x8;
typedef __attribute__((ext_vector_type(4))) unsigned short u16x4;
typedef __attribute__((ext_vector_type(4))) float f32x4;

__device__ __forceinline__ float bf2f(unsigned short u) {
  union { unsigned int i; float f; } v; v.i = ((unsigned int)u) << 16; return v.f;
}
__device__ __forceinline__ unsigned short f2bf(float f) {
  union { float f; unsigned int i; } v; v.f = f;
  unsigned int r = v.i + 0x7FFFu + ((v.i >> 16) & 1u);
  return (unsigned short)(r >> 16);
}

// async global->LDS, 16 B per lane. LDS dest is wave-uniform base + lane*16.
__device__ __forceinline__ void load_lds16(const void* g, void* l) {
  __builtin_amdgcn_global_load_lds((const __attribute__((address_space(1))) unsigned int*)g,
                                   (__attribute__((address_space(3))) unsigned int*)l, 16, 0, 0);
}

// native v_exp_f32 (2^x), no libm range handling
__device__ __forceinline__ float exp2n(float x) { return __builtin_amdgcn_exp2f(x); }

// ---------------------------------------------------------------------------
// Fused fp32 -> bf16 for all 5 input arrays; blockIdx.y selects the array.
// ---------------------------------------------------------------------------
__global__ __launch_bounds__(256) void convert5(
    const float* __restrict__ s0, unsigned short* __restrict__ d0, int n0,
    const float* __restrict__ s1, unsigned short* __restrict__ d1, int n1,
    const float* __restrict__ s2, unsigned short* __restrict__ d2, int n2,
    const float* __restrict__ s3, unsigned short* __restrict__ d3, int n3,
    const float* __restrict__ s4, unsigned short* __restrict__ d4, int n4_) {
  const float* s; unsigned short* d; int n;
  switch (blockIdx.y) {
    case 0: s = s0; d = d0; n = n0; break;
    case 1: s = s1; d = d1; n = n1; break;
    case 2: s = s2; d = d2; n = n2; break;
    case 3: s = s3; d = d3; n = n3; break;
    default: s = s4; d = d4; n = n4_; break;
  }
  int i = blockIdx.x * blockDim.x + threadIdx.x;
  int stride = gridDim.x * blockDim.x;
  for (; i < n; i += stride) {
    f32x4 v = *(const f32x4*)(s + 4 * (size_t)i);
    u16x4 o;
    o.x = f2bf(v.x); o.y = f2bf(v.y); o.z = f2bf(v.z); o.w = f2bf(v.w);
    *(u16x4*)(d + 4 * (size_t)i) = o;
  }
}

// ---------------------------------------------------------------------------
// out4 += part4 (fp32), grid-stride. Reduce for split-K.
// ---------------------------------------------------------------------------
__global__ __launch_bounds__(256) void reduce_add(float* __restrict__ out,
                                                  const float* __restrict__ part, int n4) {
  int i = blockIdx.x * blockDim.x + threadIdx.x;
  int stride = gridDim.x * blockDim.x;
  for (; i < n4; i += stride) {
    f32x4 a = *(const f32x4*)(out + 4 * (size_t)i);
    f32x4 b = *(const f32x4*)(part + 4 * (size_t)i);
    a.x += b.x; a.y += b.y; a.z += b.z; a.w += b.w;
    *(f32x4*)(out + 4 * (size_t)i) = a;
  }
}

// ---------------------------------------------------------------------------
// 256x256-tile GEMM, faithful m201-style 8-phase schedule (attempt 2).
// 8 phases per iteration covering 2 K-tiles (BK=64 each); quadrant order
// (0,0),(0,1),(1,1),(1,0) per tile. Each phase:
//   { ds_read this phase's NEW frags (4/8/12 x ds_read_b128)   <- BEFORE bar
//     issue 1 half-tile stage (2 x global_load_lds)            <- BEFORE bar
//     s_barrier            (reads complete during barrier wait)
//     setprio(1); 16 MFMA; setprio(0)   (pure-MFMA region)
//     [vmcnt(6) at phases 3/7 only -- counted, never 0 mid-loop]
//     s_barrier; sched_barrier(0) }
// Stage slots (T0=kt,T1=kt+1 -> fixed bufs 0/1; T2,T3 = +2):
//   p0:Bh0(T1) p1:Ah0(T2) p2:Bh1(T2) p3:Ah1(T2)
//   p4:Bh0(T2) p5:Ah0(T3) p6:Bh1(T3) p7:Ah1(T3)
// Every stage targets a slot whose last LDS read finished >=1 closing
// barrier earlier; every fresh read is >=4 phases after its stage and
// guarded by vmcnt(6)+barrier at p3/p7 (outstanding = exactly 3 stages = 6).
// Prologue: 4 T0-halves + 3 T1-halves, then vmcnt(6)+barrier.
// Last iter: p1..p7 stages suppressed; p3 uses vmcnt(0) (else under-drain).
// SPLIT: gridDim.z=2 halves K; z=0 -> C0 (fp32 partial), z=1 -> C1.
// ---------------------------------------------------------------------------
template <bool OUT_F32, bool SPLIT>
__global__ __launch_bounds__(512, 2) void gemm256_8p(
    const unsigned short* __restrict__ A, const unsigned short* __restrict__ B,
    void* __restrict__ C0, void* __restrict__ C1,
    int lda, int ldb, int ldc, int Kloop) {
  __shared__ alignas(16) unsigned short As[2][256 * 64];
  __shared__ alignas(16) unsigned short Bs[2][256 * 64];

  const int t = threadIdx.x;
  const int lane = t & 63, w = t >> 6;
  const int fr = lane & 15, g = lane >> 4;
  const int wr = (w >> 2) * 64;                      // row base within A-half
  const int wc = (w & 3) * 32;                       // col base within B-half
  const size_t m0 = (size_t)blockIdx.y * 256;
  const size_t n0 = (size_t)blockIdx.x * 256;
  const int kbase = SPLIT ? (int)blockIdx.z * Kloop : 0;
  void* Cv = (SPLIT && blockIdx.z) ? C1 : C0;

  // staging geometry (identical to proven gemm256; measured 0 conflicts)
  const int srow = w * 8 + (lane >> 3);
  const int sch = (lane & 7) ^ ((lane >> 3) & 7);
  const unsigned short* gA[4];
  const unsigned short* gB[4];
#pragma unroll
  for (int i = 0; i < 4; i++) {
    gA[i] = A + (m0 + i * 64 + srow) * (size_t)lda + kbase + sch * 8;
    gB[i] = B + (n0 + i * 64 + srow) * (size_t)ldb + kbase + sch * 8;
  }

  // one half-tile stage = 128 rows = 2 loads/thread
  auto stA = [&](int half, int k0, int bi) {
    load_lds16(gA[2 * half] + k0,     &As[bi][(half * 1024 + w * 64) * 8]);
    load_lds16(gA[2 * half + 1] + k0, &As[bi][(half * 1024 + 512 + w * 64) * 8]);
  };
  auto stB = [&](int half, int k0, int bi) {
    load_lds16(gB[2 * half] + k0,     &Bs[bi][(half * 1024 + w * 64) * 8]);
    load_lds16(gB[2 * half + 1] + k0, &Bs[bi][(half * 1024 + 512 + w * 64) * 8]);
  };

  const int ck0 = ((0 + g) ^ (fr & 7)) * 8;          // swizzled chunk, ks=0
  const int ck1 = ((4 + g) ^ (fr & 7)) * 8;          // swizzled chunk, ks=1

  f32x4 acc0[4][2] = {}, acc1[4][2] = {}, acc2[4][2] = {}, acc3[4][2] = {};
  const int nk = Kloop / 64;                         // >= 4, even
  const int niter = nk / 2;

#define RD_A(BASE, HOFF)                                                      \
  _Pragma("unroll")                                                           \
  for (int mf = 0; mf < 4; mf++) {                                            \
    Af[mf][0] = *(const short8*)&BASE[(HOFF + wr + mf * 16 + fr) * 64 + ck0]; \
    Af[mf][1] = *(const short8*)&BASE[(HOFF + wr + mf * 16 + fr) * 64 + ck1]; \
  }
#define RD_B(BASE, HOFF)                                                      \
  _Pragma("unroll")                                                           \
  for (int nf = 0; nf < 2; nf++) {                                            \
    Bf[nf][0] = *(const short8*)&BASE[(HOFF + wc + nf * 16 + fr) * 64 + ck0]; \
    Bf[nf][1] = *(const short8*)&BASE[(HOFF + wc + nf * 16 + fr) * 64 + ck1]; \
  }
#define MMA_QUAD(ACCQ)                                                        \
  __builtin_amdgcn_s_setprio(1);                                              \
  _Pragma("unroll")                                                           \
  for (int mf = 0; mf < 4; mf++)                                              \
    _Pragma("unroll")                                                         \
    for (int nf = 0; nf < 2; nf++) {                                          \
      ACCQ[mf][nf] = __builtin_amdgcn_mfma_f32_16x16x32_bf16(Af[mf][0], Bf[nf][0], ACCQ[mf][nf], 0, 0, 0); \
      ACCQ[mf][nf] = __builtin_amdgcn_mfma_f32_16x16x32_bf16(Af[mf][1], Bf[nf][1], ACCQ[mf][nf], 0, 0, 0); \
    }                                                                         \
  __builtin_amdgcn_s_setprio(0);
#define BAR1 __builtin_amdgcn_s_barrier();
#define BAR2 __builtin_amdgcn_s_barrier(); __builtin_amdgcn_sched_barrier(0);

  // prologue: T0 fully (4 halves, 8 loads) + T1 {Ah0,Bh1,Ah1} (6 loads)
  stA(0, 0, 0); stA(1, 0, 0); stB(0, 0, 0); stB(1, 0, 0);
  stA(0, 64, 1); stB(1, 64, 1); stA(1, 64, 1);
  asm volatile("s_waitcnt vmcnt(6)" ::: "memory");   // T0 landed; T1x3 in flight
  BAR2

  const unsigned short* A0c = As[0]; const unsigned short* B0c = Bs[0];
  const unsigned short* A1c = As[1]; const unsigned short* B1c = Bs[1];

  for (int it = 0; it < niter; it++) {
    const int kt = 2 * it;
    const bool last = (it == niter - 1);
    const int kT1 = (kt + 1) * 64, kT2 = (kt + 2) * 64, kT3 = (kt + 3) * 64;
    short8 Af[4][2], Bf[2][2];

    // p0: T0 (0,0) -- 12 reads; stage Bh0(T1)
    RD_A(A0c, 0) RD_B(B0c, 0)
    stB(0, kT1, 1);
    BAR1 MMA_QUAD(acc0) BAR2
    // p1: T0 (0,1) -- A held; stage Ah0(T2)
    RD_B(B0c, 128)
    if (!last) stA(0, kT2, 0);
    BAR1 MMA_QUAD(acc1) BAR2
    // p2: T0 (1,1) -- B held; stage Bh1(T2)
    RD_A(A0c, 128)
    if (!last) stB(1, kT2, 0);
    BAR1 MMA_QUAD(acc2) BAR2
    // p3: T0 (1,0) -- re-read Bh0; stage Ah1(T2); counted drain for p4
    RD_B(B0c, 0)
    if (!last) stA(1, kT2, 0);
    BAR1 MMA_QUAD(acc3)
    if (last) asm volatile("s_waitcnt vmcnt(0)" ::: "memory");
    else      asm volatile("s_waitcnt vmcnt(6)" ::: "memory");
    BAR2
    // p4: T1 (0,0) -- 12 reads; stage Bh0(T2)
    RD_A(A1c, 0) RD_B(B1c, 0)
    if (!last) stB(0, kT2, 0);
    BAR1 MMA_QUAD(acc0) BAR2
    // p5: T1 (0,1) -- stage Ah0(T3)
    RD_B(B1c, 128)
    if (kt + 3 < nk) stA(0, kT3, 1);
    BAR1 MMA_QUAD(acc1) BAR2
    // p6: T1 (1,1) -- stage Bh1(T3)
    RD_A(A1c, 128)
    if (kt + 3 < nk) stB(1, kT3, 1);
    BAR1 MMA_QUAD(acc2) BAR2
    // p7: T1 (1,0) -- stage Ah1(T3); counted drain for next p0
    RD_B(B1c, 0)
    if (kt + 3 < nk) stA(1, kT3, 1);
    BAR1 MMA_QUAD(acc3)
    if (!last) asm volatile("s_waitcnt vmcnt(6)" ::: "memory");
    BAR2
  }

#define STORE_Q(ACCQ, RQ, CQ)                                                 \
  _Pragma("unroll")                                                           \
  for (int mf = 0; mf < 4; mf++)                                              \
    _Pragma("unroll")                                                         \
    for (int nf = 0; nf < 2; nf++) {                                          \
      size_t row = m0 + RQ + wr + mf * 16 + g * 4;                            \
      size_t col = n0 + CQ + wc + nf * 16 + fr;                               \
      _Pragma("unroll")                                                       \
      for (int r = 0; r < 4; r++) {                                           \
        if (OUT_F32) ((float*)Cv)[(row + r) * ldc + col] = ACCQ[mf][nf][r];   \
        else ((unsigned short*)Cv)[(row + r) * ldc + col] = f2bf(ACCQ[mf][nf][r]); \
      }                                                                       \
    }

  STORE_Q(acc0, 0, 0)
  STORE_Q(acc1, 0, 128)
  STORE_Q(acc2, 128, 128)
  STORE_Q(acc3, 128, 0)

#undef RD_A
#undef RD_B
#undef MMA_QUAD
#undef BAR1
#undef BAR2
#undef STORE_Q
}

// ---------------------------------------------------------------------------
// 128x128-tile GEMM (proven R0-R3): C = A[M,K] * B[N,K]^T.
// Used for the KV slice of K1 (N=1024 -> 256 blocks, 2/CU, exactly 1 round).
// ---------------------------------------------------------------------------
template <bool OUT_F32>
__global__ __launch_bounds__(256) void gemm_bt_bf16(
    const unsigned short* __restrict__ A, const unsigned short* __restrict__ B,
    void* __restrict__ Cv, int lda, int ldb, int ldc, int K) {
  __shared__ alignas(16) unsigned short As[128 * 32];
  __shared__ alignas(16) unsigned short Bs[128 * 32];

  const int t    = threadIdx.x;
  const int lane = t & 63;
  const int w    = t >> 6;
  const int wm   = (w >> 1) * 64;
  const int wn   = (w & 1) * 64;
  const size_t m0 = (size_t)blockIdx.y * 128;
  const size_t n0 = (size_t)blockIdx.x * 128;

  f32x4 acc[4][4] = {};

  const int srow = w * 32 + (lane >> 2);
  const int scol = (lane & 3) * 8;
  const unsigned short* gA0 = &A[(m0 + srow) * (size_t)lda + scol];
  const unsigned short* gA1 = gA0 + 16 * (size_t)lda;
  const unsigned short* gB0 = &B[(n0 + srow) * (size_t)ldb + scol];
  const unsigned short* gB1 = gB0 + 16 * (size_t)ldb;
  unsigned short* lA0 = &As[(w * 32) * 32];
  unsigned short* lA1 = &As[(w * 32 + 16) * 32];
  unsigned short* lB0 = &Bs[(w * 32) * 32];
  unsigned short* lB1 = &Bs[(w * 32 + 16) * 32];

  const int fr = lane & 15;
  const int kb = (lane >> 4) * 8;

  for (int k0 = 0; k0 < K; k0 += 32) {
    load_lds16(gA0 + k0, lA0);
    load_lds16(gA1 + k0, lA1);
    load_lds16(gB0 + k0, lB0);
    load_lds16(gB1 + k0, lB1);
    __syncthreads();
    short8 af[4], bf[4];
#pragma unroll
    for (int mt = 0; mt < 4; mt++) af[mt] = *(const short8*)&As[(wm + mt * 16 + fr) * 32 + kb];
#pragma unroll
    for (int nt = 0; nt < 4; nt++) bf[nt] = *(const short8*)&Bs[(wn + nt * 16 + fr) * 32 + kb];
#pragma unroll
    for (int mt = 0; mt < 4; mt++)
#pragma unroll
      for (int nt = 0; nt < 4; nt++)
        acc[mt][nt] = __builtin_amdgcn_mfma_f32_16x16x32_bf16(af[mt], bf[nt], acc[mt][nt], 0, 0, 0);
    __syncthreads();
  }

  const int r4 = (lane >> 4) * 4;
  const int cc = lane & 15;
#pragma unroll
  for (int mt = 0; mt < 4; mt++)
#pragma unroll
    for (int nt = 0; nt < 4; nt++) {
      size_t row = m0 + wm + mt * 16 + r4;
      size_t col = n0 + wn + nt * 16 + cc;
#pragma unroll
      for (int r = 0; r < 4; r++) {
        if (OUT_F32) ((float*)Cv)[(row + r) * ldc + col] = acc[mt][nt][r];
        else ((unsigned short*)Cv)[(row + r) * ldc + col] = f2bf(acc[mt][nt][r]);
      }
    }
}

// ---------------------------------------------------------------------------
// RoPE cos/sin table per token: tab[tok*64+j] = {cos,sin}(pos[tok]*invfreq_j).
// ---------------------------------------------------------------------------
__global__ __launch_bounds__(64) void rope_tab(const int* __restrict__ pos,
                                               float2* __restrict__ tab) {
  const int tok = blockIdx.x;
  const int j = threadIdx.x;
  float p = (float)pos[tok];
  float inv_freq = expf((float)j * (-13.815510557964274f / 64.0f));  // 1e6^(-j/64)
  float ang = p * inv_freq;
  float2 cs; cs.x = cosf(ang); cs.y = sinf(ang);
  tab[tok * 64 + j] = cs;
}

// ---------------------------------------------------------------------------
// RMSNorm + RoPE, IN PLACE on qkv. 256 thr = 4 waves = 4 heads per block.
// ---------------------------------------------------------------------------
__global__ __launch_bounds__(256) void normrope(
    unsigned short* __restrict__ qkv, const float2* __restrict__ tab,
    const unsigned short* __restrict__ qw, const unsigned short* __restrict__ kw) {
  const int wv   = threadIdx.x >> 6;
  const int lane = threadIdx.x & 63;
  const int h    = blockIdx.x * 4 + wv;              // 0..35 (32 q + 4 k)
  const int tok  = blockIdx.z * SEQ + blockIdx.y;

  const unsigned short* w = (h < NH) ? qw : kw;
  const size_t src = (size_t)tok * QKV_O + (size_t)h * HD;

  float x1 = bf2f(qkv[src + lane]);
  float x2 = bf2f(qkv[src + lane + 64]);
  float ss = x1 * x1 + x2 * x2;
#pragma unroll
  for (int off = 32; off; off >>= 1) ss += __shfl_xor(ss, off);
  float r = rsqrtf(ss * (1.0f / 128.0f) + 1e-6f);
  float n1 = x1 * r * bf2f(w[lane]);
  float n2 = x2 * r * bf2f(w[lane + 64]);

  float2 cs = tab[tok * 64 + lane];
  qkv[src + lane]      = f2bf(n1 * cs.x - n2 * cs.y);
  qkv[src + lane + 64] = f2bf(n2 * cs.x + n1 * cs.y);
}

// ---------------------------------------------------------------------------
// V transpose: vt[b][kvh][d][s] <- qkv v-slot. One block per (kv-tile 64, kvh, b).
// ---------------------------------------------------------------------------
__global__ __launch_bounds__(256) void transpose_v(const unsigned short* __restrict__ qkv,
                                                   unsigned short* __restrict__ vt) {
  __shared__ alignas(16) unsigned short Vs[64][136];
  const int k0 = blockIdx.x * 64, kvh = blockIdx.y, b = blockIdx.z;
  const int t = threadIdx.x;
  const int voff = (NH + NKV) * HD + kvh * HD;
  {
    const int row = t >> 2, cb = (t & 3) * 8;
    const size_t gb = (size_t)(b * SEQ + k0 + row) * QKV_O + voff;
#pragma unroll
    for (int r = 0; r < 4; r++)
      *(uint4*)&Vs[row][cb + 32 * r] = *(const uint4*)&qkv[gb + cb + 32 * r];
  }
  __syncthreads();
  const int d = t >> 1, half = t & 1;
  const size_t ob = ((size_t)((b * NKV + kvh) * HD + d)) * SEQ + k0 + half * 32;
#pragma unroll
  for (int i = 0; i < 4; i++) {
    u16x8 vv;
#pragma unroll
    for (int j = 0; j < 8; j++) vv[j] = Vs[half * 32 + i * 8 + j][d];
    *(u16x8*)&vt[ob + i * 8] = vv;
  }
}

// ---------------------------------------------------------------------------
// MFMA causal GQA flash attention (v8, frozen: proven 110.4 us).
// ---------------------------------------------------------------------------
__global__ __launch_bounds__(512, 4) void flash_mfma(unsigned short* __restrict__ qkv,
                                                     const unsigned short* __restrict__ vt) {
  __shared__ alignas(16) unsigned short Kbuf[2][64 * 128];
  __shared__ alignas(16) unsigned short Vbuf[2][128 * 64];
  __shared__ alignas(16) unsigned short Ps[8][16 * 64];

  const int p = (int)blockIdx.x;                       // pair index 0..7
  const int h = blockIdx.y, b = blockIdx.z;
  const int t = threadIdx.x;
  const int lane = t & 63, w = t >> 6;
  const int c = lane & 15, g = lane >> 4;
  const int kvh = h >> 3;                              // GQA 32->4
  const int koff = NH * HD + kvh * HD;
  const float scale2 = 0.12751745f;                    // 128^-0.5 * log2(e)
  const int swz = c & 7;                               // 3-bit swz (V, P tiles)
  const int nqt = SEQ / 128;                           // 16

  const int rK0 = t >> 4,         jK0 = (t & 15) ^ (rK0 & 15);
  const int rK1 = (t + 512) >> 4, jK1 = ((t + 512) & 15) ^ (rK1 & 15);
  const int dV0 = t >> 3,         jV0 = (t & 7) ^ (dV0 & 7);
  const int dV1 = (t + 512) >> 3, jV1 = ((t + 512) & 7) ^ (dV1 & 7);
  const unsigned short* gK0 = qkv + (size_t)(b * SEQ + rK0) * QKV_O + koff + jK0 * 8;
  const unsigned short* gK1 = qkv + (size_t)(b * SEQ + rK1) * QKV_O + koff + jK1 * 8;
  const unsigned short* gV0 = vt + ((size_t)(b * NKV + kvh) * HD + dV0) * SEQ + jV0 * 8;
  const unsigned short* gV1 = vt + ((size_t)(b * NKV + kvh) * HD + dV1) * SEQ + jV1 * 8;

  auto stage = [&](int k0s, int bi) {
    load_lds16(gK0 + (size_t)k0s * QKV_O, &Kbuf[bi][(w * 64) * 8]);
    load_lds16(gK1 + (size_t)k0s * QKV_O, &Kbuf[bi][(w * 64 + 512) * 8]);
    load_lds16(gV0 + k0s, &Vbuf[bi][(w * 64) * 8]);
    load_lds16(gV1 + k0s, &Vbuf[bi][(w * 64 + 512) * 8]);
  };

  for (int job = 0; job < 2; job++) {
    const int qt = job == 0 ? (nqt - 1 - p) : p;       // heavy job first
    const int q0 = qt * 128;
    const int nkt = 2 * qt + 2;

    stage(0, 0);   // prologue: tile 0 -> buf 0

    short8 qf[4];
    {
      const size_t qr = (size_t)(b * SEQ + q0 + w * 16 + c) * QKV_O + (size_t)h * HD;
#pragma unroll
      for (int ks = 0; ks < 4; ks++)
        qf[ks] = *(const short8*)&qkv[qr + ks * 32 + g * 8];
    }

    f32x4 O[8] = {};
    float m_i = -1e30f, l_i = 0.0f;                    // m in log2 domain

    for (int kt = 0; kt < nkt; kt++) {
      const int cur = kt & 1;
      asm volatile("s_waitcnt vmcnt(0)" ::: "memory");
      __builtin_amdgcn_s_barrier();
      __builtin_amdgcn_sched_barrier(0);
      if (kt + 1 < nkt) stage((kt + 1) * 64, cur ^ 1);

      const unsigned short* Kc = Kbuf[cur];
      const unsigned short* Vc = Vbuf[cur];

      f32x4 sc[4];
#pragma unroll
      for (int mt = 0; mt < 4; mt++) sc[mt] = (f32x4){0.f, 0.f, 0.f, 0.f};
      __builtin_amdgcn_s_setprio(1);
#pragma unroll
      for (int ks = 0; ks < 4; ks++) {
#pragma unroll
        for (int mt = 0; mt < 4; mt++) {
          short8 kf = *(const short8*)&Kc[(mt * 16 + c) * 128 + (((ks * 4 + g) ^ c) * 8)];
          sc[mt] = __builtin_amdgcn_mfma_f32_16x16x32_bf16(kf, qf[ks], sc[mt], 0, 0, 0);
        }
      }
      __builtin_amdgcn_s_setprio(0);

      const int k0 = kt * 64;
      const int qrow = q0 + w * 16 + c;
      const bool need_mask = (k0 + 63 > q0 + w * 16);
#pragma unroll
      for (int mt = 0; mt < 4; mt++)
#pragma unroll
        for (int r = 0; r < 4; r++) {
          float s = sc[mt][r];
          if (need_mask && (k0 + mt * 16 + g * 4 + r > qrow)) s = -3.0e38f;
          sc[mt][r] = s;
        }
      // max via groups-of-3 (v_max3-fusable), depth 3
      float ma = fmaxf(fmaxf(sc[0][0], sc[0][1]), sc[0][2]);
      float mb = fmaxf(fmaxf(sc[0][3], sc[1][0]), sc[1][1]);
      float mc = fmaxf(fmaxf(sc[1][2], sc[1][3]), sc[2][0]);
      float md = fmaxf(fmaxf(sc[2][1], sc[2][2]), sc[2][3]);
      float me = fmaxf(fmaxf(sc[3][0], sc[3][1]), sc[3][2]);
      float mx = fmaxf(fmaxf(fmaxf(ma, mb), fmaxf(mc, md)), fmaxf(me, sc[3][3]));
      mx = fmaxf(mx, __shfl_xor(mx, 16));
      mx = fmaxf(mx, __shfl_xor(mx, 32));
      float mx2 = mx * scale2;                         // log2 domain

      if (!__all(mx2 - m_i <= 11.54156f)) {            // 8 * log2(e)
        float m_new = fmaxf(m_i, mx2);
        float alpha = exp2n(m_i - m_new);
        f32x4 a4;
#pragma unroll
        for (int r = 0; r < 4; r++) a4[r] = __shfl(alpha, g * 4 + r);
#pragma unroll
        for (int nt = 0; nt < 8; nt++)
#pragma unroll
          for (int r = 0; r < 4; r++) O[nt][r] *= a4[r];
        l_i *= alpha;
        m_i = m_new;
      }

      float psum = 0.0f;
#pragma unroll
      for (int mt = 0; mt < 4; mt++) {
        float pv[4];
#pragma unroll
        for (int r = 0; r < 4; r++) {
          pv[r] = exp2n(__builtin_fmaf(sc[mt][r], scale2, -m_i));
          psum += pv[r];
        }
        unsigned int pk0, pk1;
        asm("v_cvt_pk_bf16_f32 %0, %1, %2" : "=v"(pk0) : "v"(pv[0]), "v"(pv[1]));
        asm("v_cvt_pk_bf16_f32 %0, %1, %2" : "=v"(pk1) : "v"(pv[2]), "v"(pv[3]));
        uint2 pk; pk.x = pk0; pk.y = pk1;
        *(uint2*)&Ps[w][c * 64 + (((mt * 2 + (g >> 1)) ^ swz) * 8) + (g & 1) * 4] = pk;
      }
      psum += __shfl_xor(psum, 16);
      psum += __shfl_xor(psum, 32);
      l_i += psum;

      __builtin_amdgcn_s_setprio(1);
#pragma unroll
      for (int ks = 0; ks < 2; ks++) {
        short8 pf = *(const short8*)&Ps[w][c * 64 + (((ks * 4 + g) ^ swz) * 8)];
#pragma unroll
        for (int nt = 0; nt < 8; nt++) {
          short8 vf = *(const short8*)&Vc[(nt * 16 + c) * 64 + (((ks * 4 + g) ^ swz) * 8)];
          O[nt] = __builtin_amdgcn_mfma_f32_16x16x32_bf16(pf, vf, O[nt], 0, 0, 0);
        }
      }
      __builtin_amdgcn_s_setprio(0);
    }

    f32x4 l4;
#pragma unroll
    for (int r = 0; r < 4; r++) l4[r] = __shfl(l_i, g * 4 + r);
    f32x4 li;
#pragma unroll
    for (int r = 0; r < 4; r++) li[r] = 1.0f / l4[r];
#pragma unroll
    for (int nt = 0; nt < 8; nt++)
#pragma unroll
      for (int r = 0; r < 4; r++) {
        size_t addr = (size_t)(b * SEQ + q0 + w * 16 + g * 4 + r) * QKV_O + h * HD + nt * 16 + c;
        qkv[addr] = f2bf(O[nt][r] * li[r]);
      }
  }
}

// ---------------------------------------------------------------------------
extern "C" void kernel_launch(void* const* d_in, const int* in_sizes, int n_in,
                              void* d_out, int out_size, void* d_ws, size_t ws_size,
                              hipStream_t stream) {
  const float* hidden_f = (const float*)d_in[0];
  const int* positions  = (const int*)d_in[1];
  const float* wqkv_f   = (const float*)d_in[2];
  const float* wo_f     = (const float*)d_in[3];
  const float* qn_f     = (const float*)d_in[4];
  const float* kn_f     = (const float*)d_in[5];
  float* out            = (float*)d_out;  // reference output dtype is float32

  char* ws = (char*)d_ws;
  unsigned short* hidden_c = (unsigned short*)ws;                    // 16,777,216
  unsigned short* wqkv_c   = (unsigned short*)(ws + 16777216);       // 20,971,520
  unsigned short* wo_c     = (unsigned short*)(ws + 37748736);       // 16,777,216
  unsigned short* qn_c     = (unsigned short*)(ws + 54525952);       // 256
  unsigned short* kn_c     = (unsigned short*)(ws + 54526208);       // 256
  unsigned short* qkv      = (unsigned short*)(ws + 54526464);       // 41,943,040
  unsigned short* vt_g     = (unsigned short*)(ws + 96469504);       // 4,194,304  (total ~96 MiB)
  // rope table REUSES the hidden_c region (dead after K1): 2 MiB
  float2* rtab             = (float2*)ws;
  // split-K fp32 partial for K4 (33.5 MB) overlays dead hidden_c+wqkv_c
  float* p0                = (float*)ws;

  // converts: one dispatch, blockIdx.y selects array
  convert5<<<dim3(512, 5), 256, 0, stream>>>(
      hidden_f, hidden_c, NTOK * HID / 4,
      wqkv_f, wqkv_c, QKV_O * HID / 4,
      wo_f, wo_c, HID * NH * HD / 4,
      qn_f, qn_c, HD / 4,
      kn_f, kn_c, HD / 4);

  // K1a: Q slice: qkv[:, :4096] = hidden @ w_qkv[:4096]^T (4096x4096, K=2048)
  // faithful 8-phase schedule, 16x16 = 256 blocks = exactly 1 round.
  gemm256_8p<false, false><<<dim3(NH * HD / 256, NTOK / 256), 512, 0, stream>>>(
      hidden_c, wqkv_c, qkv, qkv, HID, HID, QKV_O, HID);
  // K1b: KV slice: qkv[:, 4096:5120] = hidden @ w_qkv[4096:]^T (4096x1024)
  gemm_bt_bf16<false><<<dim3(2 * NKV * HD / 128, NTOK / 128), 256, 0, stream>>>(
      hidden_c, wqkv_c + (size_t)(NH * HD) * HID, qkv + NH * HD, HID, HID, QKV_O, HID);
  // K1c: rope table (hidden_c dead now; table overwrites it)
  rope_tab<<<NTOK, 64, 0, stream>>>(positions, rtab);
  // K2: rmsnorm + rope, in place on q & k head slots (4 heads/block)
  normrope<<<dim3((NH + NKV) / 4, SEQ, BATCH), 256, 0, stream>>>(qkv, rtab, qn_c, kn_c);
  // K2b: V transpose into vt_g
  transpose_v<<<dim3(SEQ / 64, NKV, BATCH), 256, 0, stream>>>(qkv, vt_g);
  // K3: MFMA causal GQA attention (v8, frozen)
  flash_mfma<<<dim3(SEQ / 256, NH, BATCH), 512, 0, stream>>>(qkv, vt_g);
  // K4: out = attn @ w_o^T (4096 x 2048, K=4096), 8-phase split-K=2:
  // 8x16x2 = 256 blocks = 1 round; z=0 -> p0 partial, z=1 -> out.
  gemm256_8p<true, true><<<dim3(HID / 256, NTOK / 256, 2), 512, 0, stream>>>(
      qkv, wo_c, p0, out, QKV_O, NH * HD, HID, NH * HD / 2);
  // K4b: out += p0
  reduce_add<<<2048, 256, 0, stream>>>(out, p0, NTOK * HID / 4);
}

// Round 12
// 462.755 us; speedup vs baseline: 1.0821x; 1.0360x over previous
//
#include <hip/hip_runtime.h>
#include <cstdint>

#define SEQ 2048
#define BATCH 2
#define NTOK 4096      // B*S
#define HID 2048
#define NH 32
#define NKV 4
#define HD 128
#define QKV_O 5120     // (32+8)*128

typedef __attribute__((ext_vector_type(8))) short short8;
typedef __attribute__((ext_vector_type(8))) unsigned short u16x8;
typedef __attribute__((ext_vector_type(4))) unsigned short u16x4;
typedef __attribute__((ext_vector_type(4))) float f32x4;

__device__ __forceinline__ float bf2f(unsigned short u) {
  union { unsigned int i; float f; } v; v.i = ((unsigned int)u) << 16; return v.f;
}
__device__ __forceinline__ unsigned short f2bf(float f) {
  union { float f; unsigned int i; } v; v.f = f;
  unsigned int r = v.i + 0x7FFFu + ((v.i >> 16) & 1u);
  return (unsigned short)(r >> 16);
}

// async global->LDS, 16 B per lane. LDS dest is wave-uniform base + lane*16.
__device__ __forceinline__ void load_lds16(const void* g, void* l) {
  __builtin_amdgcn_global_load_lds((const __attribute__((address_space(1))) unsigned int*)g,
                                   (__attribute__((address_space(3))) unsigned int*)l, 16, 0, 0);
}

// native v_exp_f32 (2^x), no libm range handling
__device__ __forceinline__ float exp2n(float x) { return __builtin_amdgcn_exp2f(x); }

// ---------------------------------------------------------------------------
// Fused fp32 -> bf16 for all 5 input arrays; blockIdx.y selects the array.
// ---------------------------------------------------------------------------
__global__ __launch_bounds__(256) void convert5(
    const float* __restrict__ s0, unsigned short* __restrict__ d0, int n0,
    const float* __restrict__ s1, unsigned short* __restrict__ d1, int n1,
    const float* __restrict__ s2, unsigned short* __restrict__ d2, int n2,
    const float* __restrict__ s3, unsigned short* __restrict__ d3, int n3,
    const float* __restrict__ s4, unsigned short* __restrict__ d4, int n4_) {
  const float* s; unsigned short* d; int n;
  switch (blockIdx.y) {
    case 0: s = s0; d = d0; n = n0; break;
    case 1: s = s1; d = d1; n = n1; break;
    case 2: s = s2; d = d2; n = n2; break;
    case 3: s = s3; d = d3; n = n3; break;
    default: s = s4; d = d4; n = n4_; break;
  }
  int i = blockIdx.x * blockDim.x + threadIdx.x;
  int stride = gridDim.x * blockDim.x;
  for (; i < n; i += stride) {
    f32x4 v = *(const f32x4*)(s + 4 * (size_t)i);
    u16x4 o;
    o.x = f2bf(v.x); o.y = f2bf(v.y); o.z = f2bf(v.z); o.w = f2bf(v.w);
    *(u16x4*)(d + 4 * (size_t)i) = o;
  }
}

// ---------------------------------------------------------------------------
// 256x256-tile GEMM (R3-proven 2-phase): C[M,N] = A[M,K] * B[N,K]^T.
// BK=64, 512 thr (8 waves, 2M x 4N), per-wave output 128x64 (8x4 frags).
// Double-buffered 128 KiB LDS via global_load_lds(16B); measured 0 conflicts.
// ---------------------------------------------------------------------------
template <bool OUT_F32>
__global__ __launch_bounds__(512, 2) void gemm256(
    const unsigned short* __restrict__ A, const unsigned short* __restrict__ B,
    void* __restrict__ Cv, int lda, int ldb, int ldc, int Kloop) {
  __shared__ alignas(16) unsigned short As[2][256 * 64];
  __shared__ alignas(16) unsigned short Bs[2][256 * 64];

  const int t = threadIdx.x;
  const int lane = t & 63, w = t >> 6;
  const int fr = lane & 15, g = lane >> 4;
  const int wm = w >> 2, wn = w & 3;                 // 2 x 4 wave grid
  const size_t m0 = (size_t)blockIdx.y * 256;
  const size_t n0 = (size_t)blockIdx.x * 256;

  const int srow = w * 8 + (lane >> 3);
  const int sch = (lane & 7) ^ ((lane >> 3) & 7);
  const unsigned short* gA[4];
  const unsigned short* gB[4];
#pragma unroll
  for (int i = 0; i < 4; i++) {
    gA[i] = A + (m0 + i * 64 + srow) * (size_t)lda + sch * 8;
    gB[i] = B + (n0 + i * 64 + srow) * (size_t)ldb + sch * 8;
  }

  auto stage = [&](int k0, int bi) {
#pragma unroll
    for (int i = 0; i < 4; i++) {
      load_lds16(gA[i] + k0, &As[bi][(i * 512 + w * 64) * 8]);
      load_lds16(gB[i] + k0, &Bs[bi][(i * 512 + w * 64) * 8]);
    }
  };

  f32x4 acc[8][4] = {};
  stage(0, 0);

  const int nk = Kloop / 64;
  for (int kt = 0; kt < nk; kt++) {
    const int cur = kt & 1;
    asm volatile("s_waitcnt vmcnt(0)" ::: "memory");
    __builtin_amdgcn_s_barrier();
    __builtin_amdgcn_sched_barrier(0);
    if (kt + 1 < nk) stage((kt + 1) * 64, cur ^ 1);

    const unsigned short* Ac = As[cur];
    const unsigned short* Bc = Bs[cur];

    short8 bfr[4][2];
#pragma unroll
    for (int nf = 0; nf < 4; nf++) {
      const int row = wn * 64 + nf * 16 + fr;
#pragma unroll
      for (int s = 0; s < 2; s++)
        bfr[nf][s] = *(const short8*)&Bc[row * 64 + (((s * 4 + g) ^ (fr & 7)) * 8)];
    }
    __builtin_amdgcn_s_setprio(1);
#pragma unroll
    for (int mf = 0; mf < 8; mf++) {
      const int row = wm * 128 + mf * 16 + fr;
      short8 af0 = *(const short8*)&Ac[row * 64 + (((0 + g) ^ (fr & 7)) * 8)];
      short8 af1 = *(const short8*)&Ac[row * 64 + (((4 + g) ^ (fr & 7)) * 8)];
#pragma unroll
      for (int nf = 0; nf < 4; nf++) {
        acc[mf][nf] = __builtin_amdgcn_mfma_f32_16x16x32_bf16(af0, bfr[nf][0], acc[mf][nf], 0, 0, 0);
        acc[mf][nf] = __builtin_amdgcn_mfma_f32_16x16x32_bf16(af1, bfr[nf][1], acc[mf][nf], 0, 0, 0);
      }
    }
    __builtin_amdgcn_s_setprio(0);
  }

#pragma unroll
  for (int mf = 0; mf < 8; mf++)
#pragma unroll
    for (int nf = 0; nf < 4; nf++) {
      size_t row = m0 + wm * 128 + mf * 16 + g * 4;
      size_t col = n0 + wn * 64 + nf * 16 + fr;
#pragma unroll
      for (int r = 0; r < 4; r++) {
        if (OUT_F32) ((float*)Cv)[(row + r) * ldc + col] = acc[mf][nf][r];
        else ((unsigned short*)Cv)[(row + r) * ldc + col] = f2bf(acc[mf][nf][r]);
      }
    }
}

// ---------------------------------------------------------------------------
// 256x128-tile GEMM (K4 single-pass): C[M,N] = A[M,K] * B[N,K]^T, fp32 out.
// Identical structure/swizzle/sync to gemm256; B-tile halved. 8 waves 4M x 2N,
// per-wave 64x64 (4x4 frags). LDS = 96 KiB. 16x16 = 256 blocks = 1 round.
// ---------------------------------------------------------------------------
__global__ __launch_bounds__(512, 2) void gemm256x128(
    const unsigned short* __restrict__ A, const unsigned short* __restrict__ B,
    float* __restrict__ C, int lda, int ldb, int ldc, int Kloop) {
  __shared__ alignas(16) unsigned short As[2][256 * 64];
  __shared__ alignas(16) unsigned short Bs[2][128 * 64];

  const int t = threadIdx.x;
  const int lane = t & 63, w = t >> 6;
  const int fr = lane & 15, g = lane >> 4;
  const int wm = w >> 1, wn = w & 1;                 // 4 x 2 wave grid
  const size_t m0 = (size_t)blockIdx.y * 256;
  const size_t n0 = (size_t)blockIdx.x * 128;

  const int srow = t >> 3;                           // 0..63
  const int sch = (t & 7) ^ ((t >> 3) & 7);          // inverse-swizzled chunk
  const unsigned short* gA[4];
  const unsigned short* gB[2];
#pragma unroll
  for (int i = 0; i < 4; i++)
    gA[i] = A + (m0 + i * 64 + srow) * (size_t)lda + sch * 8;
#pragma unroll
  for (int i = 0; i < 2; i++)
    gB[i] = B + (n0 + i * 64 + srow) * (size_t)ldb + sch * 8;

  auto stage = [&](int k0, int bi) {
#pragma unroll
    for (int i = 0; i < 4; i++)
      load_lds16(gA[i] + k0, &As[bi][(i * 512 + w * 64) * 8]);
#pragma unroll
    for (int i = 0; i < 2; i++)
      load_lds16(gB[i] + k0, &Bs[bi][(i * 512 + w * 64) * 8]);
  };

  f32x4 acc[4][4] = {};
  stage(0, 0);

  const int nk = Kloop / 64;
  for (int kt = 0; kt < nk; kt++) {
    const int cur = kt & 1;
    asm volatile("s_waitcnt vmcnt(0)" ::: "memory");
    __builtin_amdgcn_s_barrier();
    __builtin_amdgcn_sched_barrier(0);
    if (kt + 1 < nk) stage((kt + 1) * 64, cur ^ 1);

    const unsigned short* Ac = As[cur];
    const unsigned short* Bc = Bs[cur];

    short8 bfr[4][2];
#pragma unroll
    for (int nf = 0; nf < 4; nf++) {
      const int row = wn * 64 + nf * 16 + fr;
#pragma unroll
      for (int s = 0; s < 2; s++)
        bfr[nf][s] = *(const short8*)&Bc[row * 64 + (((s * 4 + g) ^ (fr & 7)) * 8)];
    }
    __builtin_amdgcn_s_setprio(1);
#pragma unroll
    for (int mf = 0; mf < 4; mf++) {
      const int row = wm * 64 + mf * 16 + fr;
      short8 af0 = *(const short8*)&Ac[row * 64 + (((0 + g) ^ (fr & 7)) * 8)];
      short8 af1 = *(const short8*)&Ac[row * 64 + (((4 + g) ^ (fr & 7)) * 8)];
#pragma unroll
      for (int nf = 0; nf < 4; nf++) {
        acc[mf][nf] = __builtin_amdgcn_mfma_f32_16x16x32_bf16(af0, bfr[nf][0], acc[mf][nf], 0, 0, 0);
        acc[mf][nf] = __builtin_amdgcn_mfma_f32_16x16x32_bf16(af1, bfr[nf][1], acc[mf][nf], 0, 0, 0);
      }
    }
    __builtin_amdgcn_s_setprio(0);
  }

#pragma unroll
  for (int mf = 0; mf < 4; mf++)
#pragma unroll
    for (int nf = 0; nf < 4; nf++) {
      size_t row = m0 + wm * 64 + mf * 16 + g * 4;
      size_t col = n0 + wn * 64 + nf * 16 + fr;
#pragma unroll
      for (int r = 0; r < 4; r++)
        C[(row + r) * ldc + col] = acc[mf][nf][r];
    }
}

// ---------------------------------------------------------------------------
// 128x128-tile GEMM (proven R0-R3): C = A[M,K] * B[N,K]^T.
// Used for the KV slice of K1 (N=1024 -> 256 blocks, 2/CU, exactly 1 round).
// ---------------------------------------------------------------------------
template <bool OUT_F32>
__global__ __launch_bounds__(256) void gemm_bt_bf16(
    const unsigned short* __restrict__ A, const unsigned short* __restrict__ B,
    void* __restrict__ Cv, int lda, int ldb, int ldc, int K) {
  __shared__ alignas(16) unsigned short As[128 * 32];
  __shared__ alignas(16) unsigned short Bs[128 * 32];

  const int t    = threadIdx.x;
  const int lane = t & 63;
  const int w    = t >> 6;
  const int wm   = (w >> 1) * 64;
  const int wn   = (w & 1) * 64;
  const size_t m0 = (size_t)blockIdx.y * 128;
  const size_t n0 = (size_t)blockIdx.x * 128;

  f32x4 acc[4][4] = {};

  const int srow = w * 32 + (lane >> 2);
  const int scol = (lane & 3) * 8;
  const unsigned short* gA0 = &A[(m0 + srow) * (size_t)lda + scol];
  const unsigned short* gA1 = gA0 + 16 * (size_t)lda;
  const unsigned short* gB0 = &B[(n0 + srow) * (size_t)ldb + scol];
  const unsigned short* gB1 = gB0 + 16 * (size_t)ldb;
  unsigned short* lA0 = &As[(w * 32) * 32];
  unsigned short* lA1 = &As[(w * 32 + 16) * 32];
  unsigned short* lB0 = &Bs[(w * 32) * 32];
  unsigned short* lB1 = &Bs[(w * 32 + 16) * 32];

  const int fr = lane & 15;
  const int kb = (lane >> 4) * 8;

  for (int k0 = 0; k0 < K; k0 += 32) {
    load_lds16(gA0 + k0, lA0);
    load_lds16(gA1 + k0, lA1);
    load_lds16(gB0 + k0, lB0);
    load_lds16(gB1 + k0, lB1);
    __syncthreads();
    short8 af[4], bf[4];
#pragma unroll
    for (int mt = 0; mt < 4; mt++) af[mt] = *(const short8*)&As[(wm + mt * 16 + fr) * 32 + kb];
#pragma unroll
    for (int nt = 0; nt < 4; nt++) bf[nt] = *(const short8*)&Bs[(wn + nt * 16 + fr) * 32 + kb];
#pragma unroll
    for (int mt = 0; mt < 4; mt++)
#pragma unroll
      for (int nt = 0; nt < 4; nt++)
        acc[mt][nt] = __builtin_amdgcn_mfma_f32_16x16x32_bf16(af[mt], bf[nt], acc[mt][nt], 0, 0, 0);
    __syncthreads();
  }

  const int r4 = (lane >> 4) * 4;
  const int cc = lane & 15;
#pragma unroll
  for (int mt = 0; mt < 4; mt++)
#pragma unroll
    for (int nt = 0; nt < 4; nt++) {
      size_t row = m0 + wm + mt * 16 + r4;
      size_t col = n0 + wn + nt * 16 + cc;
#pragma unroll
      for (int r = 0; r < 4; r++) {
        if (OUT_F32) ((float*)Cv)[(row + r) * ldc + col] = acc[mt][nt][r];
        else ((unsigned short*)Cv)[(row + r) * ldc + col] = f2bf(acc[mt][nt][r]);
      }
    }
}

// ---------------------------------------------------------------------------
// RoPE cos/sin table per token: tab[tok*64+j] = {cos,sin}(pos[tok]*invfreq_j).
// ---------------------------------------------------------------------------
__global__ __launch_bounds__(64) void rope_tab(const int* __restrict__ pos,
                                               float2* __restrict__ tab) {
  const int tok = blockIdx.x;
  const int j = threadIdx.x;
  float p = (float)pos[tok];
  float inv_freq = expf((float)j * (-13.815510557964274f / 64.0f));  // 1e6^(-j/64)
  float ang = p * inv_freq;
  float2 cs; cs.x = cosf(ang); cs.y = sinf(ang);
  tab[tok * 64 + j] = cs;
}

// ---------------------------------------------------------------------------
// FUSED: RMSNorm+RoPE (q/k heads, in place) AND V transpose -> vt.
// 1-D grid: blocks [0, 9*NTOK) do normrope (4 heads x 1 token each);
// blocks [9*NTOK, 9*NTOK+256) do the V transpose (tile, kvh, b decode).
// Safe in one dispatch: normrope touches q/k head slots only, transpose
// reads V slots only -- disjoint memory, no ordering needed.
// ---------------------------------------------------------------------------
__global__ __launch_bounds__(256) void normrope_tv(
    unsigned short* __restrict__ qkv, const float2* __restrict__ tab,
    const unsigned short* __restrict__ qw, const unsigned short* __restrict__ kw,
    unsigned short* __restrict__ vt) {
  __shared__ alignas(16) unsigned short Vs[64][136];
  const int bid = blockIdx.x;
  const int t = threadIdx.x;

  if (bid < 9 * NTOK) {
    // ---- normrope: 4 waves = 4 heads of one token
    const int wv = t >> 6, lane = t & 63;
    const int hh = bid % 9;
    const int tok = bid / 9;                         // b*SEQ + s
    const int h = hh * 4 + wv;                       // 0..35 (32 q + 4 k)
    const unsigned short* w = (h < NH) ? qw : kw;
    const size_t src = (size_t)tok * QKV_O + (size_t)h * HD;

    float x1 = bf2f(qkv[src + lane]);
    float x2 = bf2f(qkv[src + lane + 64]);
    float ss = x1 * x1 + x2 * x2;
#pragma unroll
    for (int off = 32; off; off >>= 1) ss += __shfl_xor(ss, off);
    float r = rsqrtf(ss * (1.0f / 128.0f) + 1e-6f);
    float n1 = x1 * r * bf2f(w[lane]);
    float n2 = x2 * r * bf2f(w[lane + 64]);

    float2 cs = tab[tok * 64 + lane];
    qkv[src + lane]      = f2bf(n1 * cs.x - n2 * cs.y);
    qkv[src + lane + 64] = f2bf(n2 * cs.x + n1 * cs.y);
  } else {
    // ---- V transpose: vt[b][kvh][d][s] <- qkv v-slot
    const int r = bid - 9 * NTOK;                    // 0..255
    const int tile = r & 31, kvh = (r >> 5) & 3, b = r >> 7;
    const int k0 = tile * 64;
    const int voff = (NH + NKV) * HD + kvh * HD;
    {
      const int row = t >> 2, cb = (t & 3) * 8;
      const size_t gb = (size_t)(b * SEQ + k0 + row) * QKV_O + voff;
#pragma unroll
      for (int i = 0; i < 4; i++)
        *(uint4*)&Vs[row][cb + 32 * i] = *(const uint4*)&qkv[gb + cb + 32 * i];
    }
    __syncthreads();
    const int d = t >> 1, half = t & 1;
    const size_t ob = ((size_t)((b * NKV + kvh) * HD + d)) * SEQ + k0 + half * 32;
#pragma unroll
    for (int i = 0; i < 4; i++) {
      u16x8 vv;
#pragma unroll
      for (int j = 0; j < 8; j++) vv[j] = Vs[half * 32 + i * 8 + j][d];
      *(u16x8*)&vt[ob + i * 8] = vv;
    }
  }
}

// ---------------------------------------------------------------------------
// MFMA causal GQA flash attention (v8, frozen: proven 110.4 us).
// ---------------------------------------------------------------------------
__global__ __launch_bounds__(512, 4) void flash_mfma(unsigned short* __restrict__ qkv,
                                                     const unsigned short* __restrict__ vt) {
  __shared__ alignas(16) unsigned short Kbuf[2][64 * 128];
  __shared__ alignas(16) unsigned short Vbuf[2][128 * 64];
  __shared__ alignas(16) unsigned short Ps[8][16 * 64];

  const int p = (int)blockIdx.x;                       // pair index 0..7
  const int h = blockIdx.y, b = blockIdx.z;
  const int t = threadIdx.x;
  const int lane = t & 63, w = t >> 6;
  const int c = lane & 15, g = lane >> 4;
  const int kvh = h >> 3;                              // GQA 32->4
  const int koff = NH * HD + kvh * HD;
  const float scale2 = 0.12751745f;                    // 128^-0.5 * log2(e)
  const int swz = c & 7;                               // 3-bit swz (V, P tiles)
  const int nqt = SEQ / 128;                           // 16

  const int rK0 = t >> 4,         jK0 = (t & 15) ^ (rK0 & 15);
  const int rK1 = (t + 512) >> 4, jK1 = ((t + 512) & 15) ^ (rK1 & 15);
  const int dV0 = t >> 3,         jV0 = (t & 7) ^ (dV0 & 7);
  const int dV1 = (t + 512) >> 3, jV1 = ((t + 512) & 7) ^ (dV1 & 7);
  const unsigned short* gK0 = qkv + (size_t)(b * SEQ + rK0) * QKV_O + koff + jK0 * 8;
  const unsigned short* gK1 = qkv + (size_t)(b * SEQ + rK1) * QKV_O + koff + jK1 * 8;
  const unsigned short* gV0 = vt + ((size_t)(b * NKV + kvh) * HD + dV0) * SEQ + jV0 * 8;
  const unsigned short* gV1 = vt + ((size_t)(b * NKV + kvh) * HD + dV1) * SEQ + jV1 * 8;

  auto stage = [&](int k0s, int bi) {
    load_lds16(gK0 + (size_t)k0s * QKV_O, &Kbuf[bi][(w * 64) * 8]);
    load_lds16(gK1 + (size_t)k0s * QKV_O, &Kbuf[bi][(w * 64 + 512) * 8]);
    load_lds16(gV0 + k0s, &Vbuf[bi][(w * 64) * 8]);
    load_lds16(gV1 + k0s, &Vbuf[bi][(w * 64 + 512) * 8]);
  };

  for (int job = 0; job < 2; job++) {
    const int qt = job == 0 ? (nqt - 1 - p) : p;       // heavy job first
    const int q0 = qt * 128;
    const int nkt = 2 * qt + 2;

    stage(0, 0);   // prologue: tile 0 -> buf 0

    short8 qf[4];
    {
      const size_t qr = (size_t)(b * SEQ + q0 + w * 16 + c) * QKV_O + (size_t)h * HD;
#pragma unroll
      for (int ks = 0; ks < 4; ks++)
        qf[ks] = *(const short8*)&qkv[qr + ks * 32 + g * 8];
    }

    f32x4 O[8] = {};
    float m_i = -1e30f, l_i = 0.0f;                    // m in log2 domain

    for (int kt = 0; kt < nkt; kt++) {
      const int cur = kt & 1;
      asm volatile("s_waitcnt vmcnt(0)" ::: "memory");
      __builtin_amdgcn_s_barrier();
      __builtin_amdgcn_sched_barrier(0);
      if (kt + 1 < nkt) stage((kt + 1) * 64, cur ^ 1);

      const unsigned short* Kc = Kbuf[cur];
      const unsigned short* Vc = Vbuf[cur];

      f32x4 sc[4];
#pragma unroll
      for (int mt = 0; mt < 4; mt++) sc[mt] = (f32x4){0.f, 0.f, 0.f, 0.f};
      __builtin_amdgcn_s_setprio(1);
#pragma unroll
      for (int ks = 0; ks < 4; ks++) {
#pragma unroll
        for (int mt = 0; mt < 4; mt++) {
          short8 kf = *(const short8*)&Kc[(mt * 16 + c) * 128 + (((ks * 4 + g) ^ c) * 8)];
          sc[mt] = __builtin_amdgcn_mfma_f32_16x16x32_bf16(kf, qf[ks], sc[mt], 0, 0, 0);
        }
      }
      __builtin_amdgcn_s_setprio(0);

      const int k0 = kt * 64;
      const int qrow = q0 + w * 16 + c;
      const bool need_mask = (k0 + 63 > q0 + w * 16);
#pragma unroll
      for (int mt = 0; mt < 4; mt++)
#pragma unroll
        for (int r = 0; r < 4; r++) {
          float s = sc[mt][r];
          if (need_mask && (k0 + mt * 16 + g * 4 + r > qrow)) s = -3.0e38f;
          sc[mt][r] = s;
        }
      // max via groups-of-3 (v_max3-fusable), depth 3
      float ma = fmaxf(fmaxf(sc[0][0], sc[0][1]), sc[0][2]);
      float mb = fmaxf(fmaxf(sc[0][3], sc[1][0]), sc[1][1]);
      float mc = fmaxf(fmaxf(sc[1][2], sc[1][3]), sc[2][0]);
      float md = fmaxf(fmaxf(sc[2][1], sc[2][2]), sc[2][3]);
      float me = fmaxf(fmaxf(sc[3][0], sc[3][1]), sc[3][2]);
      float mx = fmaxf(fmaxf(fmaxf(ma, mb), fmaxf(mc, md)), fmaxf(me, sc[3][3]));
      mx = fmaxf(mx, __shfl_xor(mx, 16));
      mx = fmaxf(mx, __shfl_xor(mx, 32));
      float mx2 = mx * scale2;                         // log2 domain

      if (!__all(mx2 - m_i <= 11.54156f)) {            // 8 * log2(e)
        float m_new = fmaxf(m_i, mx2);
        float alpha = exp2n(m_i - m_new);
        f32x4 a4;
#pragma unroll
        for (int r = 0; r < 4; r++) a4[r] = __shfl(alpha, g * 4 + r);
#pragma unroll
        for (int nt = 0; nt < 8; nt++)
#pragma unroll
          for (int r = 0; r < 4; r++) O[nt][r] *= a4[r];
        l_i *= alpha;
        m_i = m_new;
      }

      float psum = 0.0f;
#pragma unroll
      for (int mt = 0; mt < 4; mt++) {
        float pv[4];
#pragma unroll
        for (int r = 0; r < 4; r++) {
          pv[r] = exp2n(__builtin_fmaf(sc[mt][r], scale2, -m_i));
          psum += pv[r];
        }
        unsigned int pk0, pk1;
        asm("v_cvt_pk_bf16_f32 %0, %1, %2" : "=v"(pk0) : "v"(pv[0]), "v"(pv[1]));
        asm("v_cvt_pk_bf16_f32 %0, %1, %2" : "=v"(pk1) : "v"(pv[2]), "v"(pv[3]));
        uint2 pk; pk.x = pk0; pk.y = pk1;
        *(uint2*)&Ps[w][c * 64 + (((mt * 2 + (g >> 1)) ^ swz) * 8) + (g & 1) * 4] = pk;
      }
      psum += __shfl_xor(psum, 16);
      psum += __shfl_xor(psum, 32);
      l_i += psum;

      __builtin_amdgcn_s_setprio(1);
#pragma unroll
      for (int ks = 0; ks < 2; ks++) {
        short8 pf = *(const short8*)&Ps[w][c * 64 + (((ks * 4 + g) ^ swz) * 8)];
#pragma unroll
        for (int nt = 0; nt < 8; nt++) {
          short8 vf = *(const short8*)&Vc[(nt * 16 + c) * 64 + (((ks * 4 + g) ^ swz) * 8)];
          O[nt] = __builtin_amdgcn_mfma_f32_16x16x32_bf16(pf, vf, O[nt], 0, 0, 0);
        }
      }
      __builtin_amdgcn_s_setprio(0);
    }

    f32x4 l4;
#pragma unroll
    for (int r = 0; r < 4; r++) l4[r] = __shfl(l_i, g * 4 + r);
    f32x4 li;
#pragma unroll
    for (int r = 0; r < 4; r++) li[r] = 1.0f / l4[r];
#pragma unroll
    for (int nt = 0; nt < 8; nt++)
#pragma unroll
      for (int r = 0; r < 4; r++) {
        size_t addr = (size_t)(b * SEQ + q0 + w * 16 + g * 4 + r) * QKV_O + h * HD + nt * 16 + c;
        qkv[addr] = f2bf(O[nt][r] * li[r]);
      }
  }
}

// ---------------------------------------------------------------------------
extern "C" void kernel_launch(void* const* d_in, const int* in_sizes, int n_in,
                              void* d_out, int out_size, void* d_ws, size_t ws_size,
                              hipStream_t stream) {
  const float* hidden_f = (const float*)d_in[0];
  const int* positions  = (const int*)d_in[1];
  const float* wqkv_f   = (const float*)d_in[2];
  const float* wo_f     = (const float*)d_in[3];
  const float* qn_f     = (const float*)d_in[4];
  const float* kn_f     = (const float*)d_in[5];
  float* out            = (float*)d_out;  // reference output dtype is float32

  char* ws = (char*)d_ws;
  unsigned short* hidden_c = (unsigned short*)ws;                    // 16,777,216
  unsigned short* wqkv_c   = (unsigned short*)(ws + 16777216);       // 20,971,520
  unsigned short* wo_c     = (unsigned short*)(ws + 37748736);       // 16,777,216
  unsigned short* qn_c     = (unsigned short*)(ws + 54525952);       // 256
  unsigned short* kn_c     = (unsigned short*)(ws + 54526208);       // 256
  unsigned short* qkv      = (unsigned short*)(ws + 54526464);       // 41,943,040
  unsigned short* vt_g     = (unsigned short*)(ws + 96469504);       // 4,194,304  (total ~96 MiB)
  // rope table REUSES the hidden_c region (dead after K1): 2 MiB
  float2* rtab             = (float2*)ws;

  // converts: one dispatch, blockIdx.y selects array
  convert5<<<dim3(512, 5), 256, 0, stream>>>(
      hidden_f, hidden_c, NTOK * HID / 4,
      wqkv_f, wqkv_c, QKV_O * HID / 4,
      wo_f, wo_c, HID * NH * HD / 4,
      qn_f, qn_c, HD / 4,
      kn_f, kn_c, HD / 4);

  // K1a: Q slice: qkv[:, :4096] = hidden @ w_qkv[:4096]^T (4096x4096, K=2048)
  gemm256<false><<<dim3(NH * HD / 256, NTOK / 256), 512, 0, stream>>>(
      hidden_c, wqkv_c, qkv, HID, HID, QKV_O, HID);
  // K1b: KV slice: qkv[:, 4096:5120] = hidden @ w_qkv[4096:]^T (4096x1024)
  gemm_bt_bf16<false><<<dim3(2 * NKV * HD / 128, NTOK / 128), 256, 0, stream>>>(
      hidden_c, wqkv_c + (size_t)(NH * HD) * HID, qkv + NH * HD, HID, HID, QKV_O, HID);
  // K1c: rope table (hidden_c dead now; table overwrites it)
  rope_tab<<<NTOK, 64, 0, stream>>>(positions, rtab);
  // K2: fused rmsnorm+rope (q/k) AND V transpose (disjoint qkv slots)
  normrope_tv<<<9 * NTOK + 256, 256, 0, stream>>>(qkv, rtab, qn_c, kn_c, vt_g);
  // K3: MFMA causal GQA attention (v8, frozen)
  flash_mfma<<<dim3(SEQ / 256, NH, BATCH), 512, 0, stream>>>(qkv, vt_g);
  // K4: out = attn @ w_o^T (4096 x 2048, K=4096), 256x128 tiles:
  // 16x16 = 256 blocks = exactly 1 round, single pass, no split-K/reduce.
  gemm256x128<<<dim3(HID / 128, NTOK / 256), 512, 0, stream>>>(
      qkv, wo_c, out, QKV_O, NH * HD, HID, NH * HD);
}